// Round 1
// baseline (227.513 us; speedup 1.0000x reference)
//
#include <hip/hip_runtime.h>

#define BATCH 512
#define K_OPS 16
#define D2    128
#define TSTEPS 64
#define NZB   2048   // zero-fill blocks

// ---------------------------------------------------------------------------
// K1: fused expH (blocks 0..15) + zero-fill of d_out (blocks 16..16+NZB-1)
// expH[k] = I + sum_{i=1..10} X^i / i!   with X = S @ sym(H_k), computed as
// power = power @ X / i  (matches reference Taylor loop exactly in f32).
// ---------------------------------------------------------------------------
__global__ __launch_bounds__(256, 1) void k_expH_zero(
    const float* __restrict__ H,      // [K,128,128]
    float* __restrict__ expw,         // ws: [K,128,128]
    float* __restrict__ out)          // [B,T,K,128] -> zeroed here
{
    const int bid = blockIdx.x;
    const int tid = threadIdx.x;

    if (bid >= K_OPS) {
        // ---- zero-fill path ----
        float4* o4 = (float4*)out;
        const int total = BATCH * TSTEPS * K_OPS * D2 / 4;   // 16,777,216
        int idx = (bid - K_OPS) * 256 + tid;
        const int stride = NZB * 256;                        // 524,288
        const float4 z = {0.f, 0.f, 0.f, 0.f};
        for (; idx < total; idx += stride) o4[idx] = z;
        return;
    }

    // ---- expH path: one block per operator ----
    __shared__ float X[D2][132];   // padded, rows 16B-aligned (132*4=528)
    __shared__ float P[D2][129];   // padded +1 for conflict-free column reads

    const float* Hk = H + bid * D2 * D2;

    // X = S @ sym(H):  X[i][j] = 0.5*(H[i'][j]+H[j][i']) * sign,
    // i' = i+64 (i<64, +) or i-64 (i>=64, -).   P = I.
    for (int idx = tid; idx < D2 * D2; idx += 256) {
        const int i = idx >> 7, j = idx & 127;
        const int i2 = (i < 64) ? i + 64 : i - 64;
        const float sgn = (i < 64) ? 0.5f : -0.5f;
        X[i][j] = sgn * (Hk[i2 * D2 + j] + Hk[j * D2 + i2]);
        P[i][j] = (i == j) ? 1.0f : 0.0f;
    }
    __syncthreads();

    const int ty = tid >> 4, tx = tid & 15;
    const int r0 = ty * 8, c0 = tx * 8;

    float acc[8][8];
    #pragma unroll
    for (int ri = 0; ri < 8; ++ri)
        #pragma unroll
        for (int ci = 0; ci < 8; ++ci)
            acc[ri][ci] = (r0 + ri == c0 + ci) ? 1.0f : 0.0f;   // out = I

    for (int it = 1; it <= 10; ++it) {
        const float inv = 1.0f / (float)it;
        float tmp[8][8];
        #pragma unroll
        for (int ri = 0; ri < 8; ++ri)
            #pragma unroll
            for (int ci = 0; ci < 8; ++ci) tmp[ri][ci] = 0.f;

        #pragma unroll 2
        for (int j = 0; j < D2; ++j) {
            float pv[8];
            #pragma unroll
            for (int ri = 0; ri < 8; ++ri) pv[ri] = P[r0 + ri][j];
            const float4 xa = *(const float4*)&X[j][c0];
            const float4 xb = *(const float4*)&X[j][c0 + 4];
            float xv[8];
            xv[0] = xa.x; xv[1] = xa.y; xv[2] = xa.z; xv[3] = xa.w;
            xv[4] = xb.x; xv[5] = xb.y; xv[6] = xb.z; xv[7] = xb.w;
            #pragma unroll
            for (int ri = 0; ri < 8; ++ri)
                #pragma unroll
                for (int ci = 0; ci < 8; ++ci)
                    tmp[ri][ci] = fmaf(pv[ri], xv[ci], tmp[ri][ci]);
        }
        __syncthreads();   // all reads of P done
        #pragma unroll
        for (int ri = 0; ri < 8; ++ri)
            #pragma unroll
            for (int ci = 0; ci < 8; ++ci) {
                const float v = tmp[ri][ci] * inv;
                P[r0 + ri][c0 + ci] = v;   // power for next iteration
                acc[ri][ci] += v;          // out += power
            }
        __syncthreads();
    }

    float* ek = expw + bid * D2 * D2;
    #pragma unroll
    for (int ri = 0; ri < 8; ++ri)
        #pragma unroll
        for (int ci = 0; ci < 8; ++ci)
            ek[(r0 + ri) * D2 + c0 + ci] = acc[ri][ci];
}

// ---------------------------------------------------------------------------
// K2: per-batch propagation. Block b: k = argmax(u_t[b]); thread i owns
// row i of expH[k] in VGPRs; s broadcast via LDS; 64 timestep writes.
// ---------------------------------------------------------------------------
__global__ __launch_bounds__(128, 1) void k_prop(
    const float* __restrict__ u,      // [B,K]
    const float* __restrict__ s_in,   // [B,K,128]
    const float* __restrict__ expw,   // [K,128,128]
    float* __restrict__ out)          // [B,T,K,128]
{
    const int b = blockIdx.x;
    const int i = threadIdx.x;

    // argmax over 16 (first-max wins -> strict >)
    const float* ub = u + b * K_OPS;
    float m = ub[0];
    int lab = 0;
    #pragma unroll
    for (int j = 1; j < K_OPS; ++j) {
        const float v = ub[j];
        if (v > m) { m = v; lab = j; }
    }

    __shared__ float s_lds[D2];

    // row i of expH[lab] into registers (fully unrolled -> stays in VGPRs)
    const float4* rowp = (const float4*)(expw + (lab * D2 + i) * D2);
    float row[D2];
    #pragma unroll
    for (int jj = 0; jj < 32; ++jj) {
        const float4 rv = rowp[jj];
        row[4 * jj + 0] = rv.x; row[4 * jj + 1] = rv.y;
        row[4 * jj + 2] = rv.z; row[4 * jj + 3] = rv.w;
    }

    float sval = s_in[(b * K_OPS + lab) * D2 + i];
    s_lds[i] = sval;
    __syncthreads();

    float* ob = out + ((size_t)b * TSTEPS * K_OPS + lab) * D2;

    for (int t = 0; t < TSTEPS; ++t) {
        ob[(size_t)t * K_OPS * D2 + i] = sval;     // seq[t] (t=0 is input)
        if (t == TSTEPS - 1) break;

        float acc = 0.f;
        const float4* s4 = (const float4*)s_lds;
        #pragma unroll
        for (int jj = 0; jj < 32; ++jj) {
            const float4 sv = s4[jj];
            acc = fmaf(row[4 * jj + 0], sv.x, acc);
            acc = fmaf(row[4 * jj + 1], sv.y, acc);
            acc = fmaf(row[4 * jj + 2], sv.z, acc);
            acc = fmaf(row[4 * jj + 3], sv.w, acc);
        }
        __syncthreads();   // everyone done reading s_lds
        s_lds[i] = acc;
        __syncthreads();
        sval = acc;
    }
}

extern "C" void kernel_launch(void* const* d_in, const int* in_sizes, int n_in,
                              void* d_out, int out_size, void* d_ws, size_t ws_size,
                              hipStream_t stream) {
    const float* u_t = (const float*)d_in[0];   // [512,16]
    const float* s_t = (const float*)d_in[1];   // [512,16,128]
    const float* H   = (const float*)d_in[2];   // [16,128,128]
    // d_in[3]=timesteps(64), d_in[4]=startidx(0): fixed by problem, hardcoded.

    float* out  = (float*)d_out;
    float* expw = (float*)d_ws;                 // 16*128*128*4 = 1 MB

    hipLaunchKernelGGL(k_expH_zero, dim3(K_OPS + NZB), dim3(256), 0, stream,
                       H, expw, out);
    hipLaunchKernelGGL(k_prop, dim3(BATCH), dim3(128), 0, stream,
                       u_t, s_t, expw, out);
}

// Round 3
// 97.138 us; speedup vs baseline: 2.3422x; 2.3422x over previous
//
#include <hip/hip_runtime.h>

#define BATCH  512
#define K_OPS  16
#define D2     128
#define TSTEPS 64
#define NSLAB  (BATCH * TSTEPS)          // 32768 slabs of 16*128 floats (8 KB)

#define S1 5120                          // slabs zeroed by k_prep
#define S2 9728                          // slabs zeroed by k_taylor
// k_prop zeroes [S1+S2, NSLAB) with per-batch label-channel skip

#define PREP_ZB 1024
#define TAY_CB  256                      // 16 ops x 16 strips (8 rows)
#define TAY_ZB  1024
#define PROP_CB 256                      // 2 batches per block
#define PROP_ZB 2048

typedef float vf4 __attribute__((ext_vector_type(4)));

// plain zero of whole slabs [lo,hi): slab s -> out + s*2048 floats
__device__ inline void zero_slabs(float* __restrict__ out, int lo, int hi,
                                  int zb, int nzb, int tid) {
    const vf4 z = {0.f, 0.f, 0.f, 0.f};
    for (int s = lo + zb; s < hi; s += nzb) {
        vf4* p = (vf4*)(out + (size_t)s * 2048);
        __builtin_nontemporal_store(z, p + tid);
        __builtin_nontemporal_store(z, p + tid + 256);
    }
}

// ---------------------------------------------------------------------------
// K1: X_k = S @ sym(H_k)  (+ zero slice 1)
// ---------------------------------------------------------------------------
__global__ __launch_bounds__(256) void k_prep(
    const float* __restrict__ H, float* __restrict__ X, float* __restrict__ out)
{
    const int bid = blockIdx.x, tid = threadIdx.x;
    if (bid >= K_OPS) { zero_slabs(out, 0, S1, bid - K_OPS, PREP_ZB, tid); return; }

    __shared__ float Hs[D2][D2 + 1];
    const float* Hk = H + bid * D2 * D2;
    for (int idx = tid; idx < D2 * D2; idx += 256)
        Hs[idx >> 7][idx & 127] = Hk[idx];
    __syncthreads();

    float* Xk = X + bid * D2 * D2;
    for (int idx = tid; idx < D2 * D2; idx += 256) {
        const int i = idx >> 7, j = idx & 127;
        const int i2 = (i < 64) ? i + 64 : i - 64;
        const float sgn = (i < 64) ? 0.5f : -0.5f;
        Xk[idx] = sgn * (Hs[i2][j] + Hs[j][i2]);
    }
}

// ---------------------------------------------------------------------------
// K2: all 9 remaining Taylor iterations in one launch.
// Block owns an 8-row strip of one operator: P_new rows depend only on the
// same P_old rows, so no cross-block dependency. X in LDS (64 KB), strip
// kept transposed in LDS (PsT[j][r], padded stride 12). acc = I + X + ...
// (+ zero slice 2)
// ---------------------------------------------------------------------------
__global__ __launch_bounds__(256) void k_taylor(
    const float* __restrict__ X, float* __restrict__ ACC, float* __restrict__ out)
{
    const int bid = blockIdx.x, tid = threadIdx.x;
    if (bid >= TAY_CB) { zero_slabs(out, S1, S1 + S2, bid - TAY_CB, TAY_ZB, tid); return; }

    __shared__ float Xs[D2][D2];      // 64 KB
    __shared__ float PsT[D2][12];     // [j][row_local], padded stride

    const int k  = bid >> 4;
    const int r0 = (bid & 15) * 8;
    const float* Xk = X + k * D2 * D2;

    for (int idx = tid * 4; idx < D2 * D2; idx += 1024)
        *(float4*)&Xs[idx >> 7][idx & 127] = *(const float4*)&Xk[idx];
    __syncthreads();

    const int c  = tid & 127;
    const int rg = tid >> 7;          // 0..1 -> rows rg*4..rg*4+3 of strip

    float acc[4];
    {
        float4 iv;
        float* ivp = (float*)&iv;
        #pragma unroll
        for (int rr = 0; rr < 4; ++rr) {
            const int row = r0 + rg * 4 + rr;
            const float xv = Xs[row][c];
            acc[rr] = xv + ((row == c) ? 1.0f : 0.0f);   // I + X
            ivp[rr] = xv;
        }
        *(float4*)&PsT[c][rg * 4] = iv;                   // P = X (transposed)
    }
    __syncthreads();

    #pragma unroll
    for (int it = 2; it <= 10; ++it) {
        const float inv = 1.0f / (float)it;
        float nv[4] = {0.f, 0.f, 0.f, 0.f};
        #pragma unroll 4
        for (int j = 0; j < D2; ++j) {
            const float xv = Xs[j][c];
            const float4 pv = *(const float4*)&PsT[j][rg * 4];
            nv[0] = fmaf(pv.x, xv, nv[0]);
            nv[1] = fmaf(pv.y, xv, nv[1]);
            nv[2] = fmaf(pv.z, xv, nv[2]);
            nv[3] = fmaf(pv.w, xv, nv[3]);
        }
        #pragma unroll
        for (int rr = 0; rr < 4; ++rr) { nv[rr] *= inv; acc[rr] += nv[rr]; }
        __syncthreads();
        *(float4*)&PsT[c][rg * 4] = make_float4(nv[0], nv[1], nv[2], nv[3]);
        __syncthreads();
    }

    float* Ak = ACC + k * D2 * D2;
    #pragma unroll
    for (int rr = 0; rr < 4; ++rr)
        Ak[(r0 + rg * 4 + rr) * D2 + c] = acc[rr];
}

// ---------------------------------------------------------------------------
// K3: propagation (2 batches per block, row of expH in VGPRs) + zero slice 3.
// Zero blocks skip each batch's label channel -> write-disjoint from prop.
// ---------------------------------------------------------------------------
__device__ inline int argmax16(const float* __restrict__ ub) {
    float m = ub[0]; int lab = 0;
    #pragma unroll
    for (int j = 1; j < K_OPS; ++j) {
        const float v = ub[j];
        if (v > m) { m = v; lab = j; }
    }
    return lab;
}

__global__ __launch_bounds__(256) void k_prop(
    const float* __restrict__ u, const float* __restrict__ s_in,
    const float* __restrict__ ACC, float* __restrict__ out)
{
    const int bid = blockIdx.x, tid = threadIdx.x;

    if (bid >= PROP_CB) {
        const int zb = bid - PROP_CB;
        const vf4 z = {0.f, 0.f, 0.f, 0.f};
        for (int s = S1 + S2 + zb; s < NSLAB; s += PROP_ZB) {
            const int b = s >> 6;
            const int lab = argmax16(u + b * K_OPS);
            vf4* p = (vf4*)(out + (size_t)s * 2048);
            int slot = tid;
            if ((slot >> 5) != lab) __builtin_nontemporal_store(z, p + slot);
            slot = tid + 256;
            if ((slot >> 5) != lab) __builtin_nontemporal_store(z, p + slot);
        }
        return;
    }

    const int h = tid >> 7, i = tid & 127;
    const int b = bid * 2 + h;
    const int lab = argmax16(u + b * K_OPS);

    __shared__ float s_lds[2][D2];

    const float4* rowp = (const float4*)(ACC + (lab * D2 + i) * D2);
    float row[D2];
    #pragma unroll
    for (int jj = 0; jj < 32; ++jj) {
        const float4 rv = rowp[jj];
        row[4 * jj + 0] = rv.x; row[4 * jj + 1] = rv.y;
        row[4 * jj + 2] = rv.z; row[4 * jj + 3] = rv.w;
    }

    float sval = s_in[(b * K_OPS + lab) * D2 + i];
    s_lds[h][i] = sval;
    __syncthreads();

    float* ob = out + ((size_t)b * TSTEPS * K_OPS + lab) * D2;

    for (int t = 0; t < TSTEPS; ++t) {
        __builtin_nontemporal_store(sval, ob + (size_t)t * K_OPS * D2 + i);
        if (t == TSTEPS - 1) break;

        float acc = 0.f;
        const float4* s4 = (const float4*)s_lds[h];
        #pragma unroll
        for (int jj = 0; jj < 32; ++jj) {
            const float4 sv = s4[jj];
            acc = fmaf(row[4 * jj + 0], sv.x, acc);
            acc = fmaf(row[4 * jj + 1], sv.y, acc);
            acc = fmaf(row[4 * jj + 2], sv.z, acc);
            acc = fmaf(row[4 * jj + 3], sv.w, acc);
        }
        __syncthreads();
        s_lds[h][i] = acc;
        __syncthreads();
        sval = acc;
    }
}

extern "C" void kernel_launch(void* const* d_in, const int* in_sizes, int n_in,
                              void* d_out, int out_size, void* d_ws, size_t ws_size,
                              hipStream_t stream) {
    const float* u_t = (const float*)d_in[0];   // [512,16]
    const float* s_t = (const float*)d_in[1];   // [512,16,128]
    const float* H   = (const float*)d_in[2];   // [16,128,128]

    float* out = (float*)d_out;
    float* Xw  = (float*)d_ws;                  // [16,128,128] = 1 MB
    float* Aw  = Xw + K_OPS * D2 * D2;          // [16,128,128] = 1 MB

    hipLaunchKernelGGL(k_prep,   dim3(K_OPS + PREP_ZB),  dim3(256), 0, stream, H, Xw, out);
    hipLaunchKernelGGL(k_taylor, dim3(TAY_CB + TAY_ZB),  dim3(256), 0, stream, Xw, Aw, out);
    hipLaunchKernelGGL(k_prop,   dim3(PROP_CB + PROP_ZB), dim3(256), 0, stream, u_t, s_t, Aw, out);
}

// Round 4
// 87.439 us; speedup vs baseline: 2.6020x; 1.1109x over previous
//
#include <hip/hip_runtime.h>

#define BATCH  512
#define K_OPS  16
#define D2     128
#define TSTEPS 64

typedef float vf4 __attribute__((ext_vector_type(4)));

// ---------------------------------------------------------------------------
// K1: fused X = S@sym(H) + all 10 Taylor orders. 256 blocks = 16 ops x 16
// row-strips (8 rows each). Hk staged in LDS [128][129] (pad -> conflict-free
// column reads), Xs built in LDS, strip powers kept transposed in PsT.
// ---------------------------------------------------------------------------
__global__ __launch_bounds__(256) void k_taylor(
    const float* __restrict__ H, float* __restrict__ ACC)
{
    __shared__ float Hs[D2][D2 + 1];   // 64.5 KB, +1 pad: row & col reads conflict-free
    __shared__ float Xs[D2][D2];       // 64 KB
    __shared__ float PsT[D2][12];      // [j][row_local], padded stride

    const int bid = blockIdx.x, tid = threadIdx.x;
    const int k  = bid >> 4;
    const int r0 = (bid & 15) * 8;
    const float* Hk = H + k * D2 * D2;

    for (int idx = tid; idx < D2 * D2; idx += 256)
        Hs[idx >> 7][idx & 127] = Hk[idx];
    __syncthreads();

    // X[i][j] = sgn(i) * 0.5 * (H[i^64][j] + H[j][i^64])
    for (int idx = tid; idx < D2 * D2; idx += 256) {
        const int i = idx >> 7, j = idx & 127;
        const int i2 = i ^ 64;
        const float sgn = (i < 64) ? 0.5f : -0.5f;
        Xs[i][j] = sgn * (Hs[i2][j] + Hs[j][i2]);
    }
    __syncthreads();

    const int c  = tid & 127;
    const int rg = tid >> 7;          // 0..1 -> rows rg*4..rg*4+3 of strip

    float acc[4];
    {
        float4 iv;
        float* ivp = (float*)&iv;
        #pragma unroll
        for (int rr = 0; rr < 4; ++rr) {
            const int row = r0 + rg * 4 + rr;
            const float xv = Xs[row][c];
            acc[rr] = xv + ((row == c) ? 1.0f : 0.0f);   // I + X
            ivp[rr] = xv;
        }
        *(float4*)&PsT[c][rg * 4] = iv;                   // P = X (transposed)
    }
    __syncthreads();

    #pragma unroll
    for (int it = 2; it <= 10; ++it) {
        const float inv = 1.0f / (float)it;
        float nv[4] = {0.f, 0.f, 0.f, 0.f};
        #pragma unroll 4
        for (int j = 0; j < D2; ++j) {
            const float xv = Xs[j][c];
            const float4 pv = *(const float4*)&PsT[j][rg * 4];
            nv[0] = fmaf(pv.x, xv, nv[0]);
            nv[1] = fmaf(pv.y, xv, nv[1]);
            nv[2] = fmaf(pv.z, xv, nv[2]);
            nv[3] = fmaf(pv.w, xv, nv[3]);
        }
        #pragma unroll
        for (int rr = 0; rr < 4; ++rr) { nv[rr] *= inv; acc[rr] += nv[rr]; }
        __syncthreads();
        *(float4*)&PsT[c][rg * 4] = make_float4(nv[0], nv[1], nv[2], nv[3]);
        __syncthreads();
    }

    float* Ak = ACC + k * D2 * D2;
    #pragma unroll
    for (int rr = 0; rr < 4; ++rr)
        Ak[(r0 + rg * 4 + rr) * D2 + c] = acc[rr];
}

// ---------------------------------------------------------------------------
// K2: one block per batch (512 blocks, 256 threads, 2 blocks/CU).
// Threads 0..127 run the 64-step chain (row of expH[lab] in VGPRs, state
// broadcast via LDS). Every t-step, ALL 256 threads zero slab t of this
// batch (512 vf4 slots, skipping the label channel -> byte-disjoint from
// the chain's stores). Zeroing (39 us of write BW) hides the chain (~12 us).
// ---------------------------------------------------------------------------
__global__ __launch_bounds__(256) void k_prop(
    const float* __restrict__ u, const float* __restrict__ s_in,
    const float* __restrict__ ACC, float* __restrict__ out)
{
    const int b = blockIdx.x, tid = threadIdx.x;

    // argmax over 16 (first-max wins -> strict >)
    const float* ub = u + b * K_OPS;
    float m = ub[0]; int lab = 0;
    #pragma unroll
    for (int j = 1; j < K_OPS; ++j) {
        const float v = ub[j];
        if (v > m) { m = v; lab = j; }
    }

    __shared__ float s_lds[D2];

    const bool chain = (tid < D2);     // waves 0,1 (uniform per wave)
    const int i = tid & 127;

    float row[D2];
    float sval = 0.f;
    if (chain) {
        const float4* rowp = (const float4*)(ACC + (lab * D2 + i) * D2);
        #pragma unroll
        for (int jj = 0; jj < 32; ++jj) {
            const float4 rv = rowp[jj];
            row[4 * jj + 0] = rv.x; row[4 * jj + 1] = rv.y;
            row[4 * jj + 2] = rv.z; row[4 * jj + 3] = rv.w;
        }
        sval = s_in[(b * K_OPS + lab) * D2 + i];
        s_lds[i] = sval;
    }
    __syncthreads();

    float* base = out + (size_t)b * TSTEPS * K_OPS * D2;   // batch region, 512 KB
    float* ob   = base + lab * D2;                          // label channel base
    const vf4 z = {0.f, 0.f, 0.f, 0.f};
    const int slot0 = tid, slot1 = tid + 256;
    const bool do0 = (slot0 >> 5) != lab;
    const bool do1 = (slot1 >> 5) != lab;

    for (int t = 0; t < TSTEPS; ++t) {
        // zero slab t (all threads), label channel skipped
        vf4* sp = (vf4*)(base + (size_t)t * K_OPS * D2);
        if (do0) __builtin_nontemporal_store(z, sp + slot0);
        if (do1) __builtin_nontemporal_store(z, sp + slot1);
        // chain store seq[t]
        if (chain)
            __builtin_nontemporal_store(sval, ob + (size_t)t * K_OPS * D2 + i);
        if (t == TSTEPS - 1) break;

        float acc = 0.f;
        if (chain) {
            const float4* s4 = (const float4*)s_lds;
            #pragma unroll
            for (int jj = 0; jj < 32; ++jj) {
                const float4 sv = s4[jj];
                acc = fmaf(row[4 * jj + 0], sv.x, acc);
                acc = fmaf(row[4 * jj + 1], sv.y, acc);
                acc = fmaf(row[4 * jj + 2], sv.z, acc);
                acc = fmaf(row[4 * jj + 3], sv.w, acc);
            }
        }
        __syncthreads();
        if (chain) s_lds[i] = acc;
        __syncthreads();
        sval = acc;
    }
}

extern "C" void kernel_launch(void* const* d_in, const int* in_sizes, int n_in,
                              void* d_out, int out_size, void* d_ws, size_t ws_size,
                              hipStream_t stream) {
    const float* u_t = (const float*)d_in[0];   // [512,16]
    const float* s_t = (const float*)d_in[1];   // [512,16,128]
    const float* H   = (const float*)d_in[2];   // [16,128,128]

    float* out = (float*)d_out;
    float* Aw  = (float*)d_ws;                  // [16,128,128] = 1 MB

    hipLaunchKernelGGL(k_taylor, dim3(256), dim3(256), 0, stream, H, Aw);
    hipLaunchKernelGGL(k_prop,   dim3(BATCH), dim3(256), 0, stream,
                       u_t, s_t, Aw, out);
}